// Round 2
// baseline (4287.189 us; speedup 1.0000x reference)
//
#include <hip/hip_runtime.h>

typedef short bf16x8 __attribute__((ext_vector_type(8)));   // 8 bf16 in 4 VGPRs
typedef float f32x16 __attribute__((ext_vector_type(16)));
typedef unsigned int u32;
typedef unsigned int u32x4 __attribute__((ext_vector_type(4)));

#define NB 65536
#define STR2 136                 // LDS row stride (shorts) for K=128 arrays: 272B = 17x16B (odd slots)
#define STR1 24                  // stride for K=16 arrays: 48B = 3x16B
#define OFF_W1  0                // [256][24]   drift|diff layer1 (W^T, k=9 holds b1)
#define OFF_W2D 6144             // [128][136]
#define OFF_W2F 23552            // [128][136]
#define OFF_W3D 40960            // [32][136]  (rows 8..31 zero)
#define OFF_W3F 45312            // [64][136]
#define LDS_SHORTS 54016         // 105.5 KB

// ---- semantics-safe primitives (no inline asm anywhere) ----
__device__ __forceinline__ u32 bfr(float f) {               // bf16 round-to-nearest-even, raw 16 bits
    u32 u = __builtin_bit_cast(u32, f);
    return (u + 0x7fffu + ((u >> 16) & 1u)) >> 16;
}
__device__ __forceinline__ u32 pkbf16(float a, float b) {   // a -> low16, b -> high16
    return bfr(a) | (bfr(b) << 16);
}
__device__ __forceinline__ short bf16s(float a) {
    return (short)bfr(a);
}
__device__ __forceinline__ float ftanh(float x) {
    float e = __expf(2.0f * x);                             // native v_exp after log2e scaling
    return 1.0f - 2.0f / (e + 1.0f);                        // precise division
}
__device__ __forceinline__ bf16x8 fragU(u32 a, u32 b, u32 c, u32 d) {
    u32x4 q = {a, b, c, d};
    return __builtin_bit_cast(bf16x8, q);
}
__device__ __forceinline__ bf16x8 ldsfrag(const short* p) {
    const u32x4* q = (const u32x4*)p;                       // ds_read_b128 (16B aligned by construction)
    return __builtin_bit_cast(bf16x8, *q);
}
__device__ __forceinline__ f32x16 mf(bf16x8 a, bf16x8 b, f32x16 c) {
    return __builtin_amdgcn_mfma_f32_32x32x16_bf16(a, b, c, 0, 0, 0);
}

// D tile (post-activation) -> two B-operand K-tiles for the next layer, all in registers.
// D reg r in lane (col,hi) holds neuron (r&3)+8*(r>>2)+4*hi of the 32-tile.
__device__ __forceinline__ void transition(const f32x16 d, int hi, u32* fa, u32* fb) {
    u32 P[8], Q[8];
    #pragma unroll
    for (int i = 0; i < 8; ++i)
        P[i] = pkbf16(ftanh(d[2*i]), ftanh(d[2*i+1]));
    #pragma unroll
    for (int i = 0; i < 8; ++i)
        Q[i] = __shfl_xor(P[i], 32, 64);                    // partner half's value
    // B-frag dword c of lane (col,hi) must hold k = hi*8 + 2c, 2c+1 of the k-tile
    fa[0] = hi ? Q[2] : P[0];   // (0,1)/(8,9)
    fa[1] = hi ? Q[3] : P[1];   // (2,3)/(10,11)
    fa[2] = hi ? P[2] : Q[0];   // (4,5)/(12,13)
    fa[3] = hi ? P[3] : Q[1];   // (6,7)/(14,15)
    fb[0] = hi ? Q[6] : P[4];   // (16,17)/(24,25)
    fb[1] = hi ? Q[7] : P[5];   // (18,19)/(26,27)
    fb[2] = hi ? P[6] : Q[4];   // (20,21)/(28,29)
    fb[3] = hi ? P[7] : Q[5];   // (22,23)/(30,31)
}

__global__ __launch_bounds__(512, 2)
void sde_fused(const float* __restrict__ noise, const float* __restrict__ dW,
               const float* __restrict__ dw1, const float* __restrict__ db1,
               const float* __restrict__ dw2, const float* __restrict__ db2,
               const float* __restrict__ dw3, const float* __restrict__ db3,
               const float* __restrict__ fw1, const float* __restrict__ fb1,
               const float* __restrict__ fw2, const float* __restrict__ fb2,
               const float* __restrict__ fw3, const float* __restrict__ fb3,
               const float* __restrict__ iw1, const float* __restrict__ ib1,
               const float* __restrict__ iw2, const float* __restrict__ ib2,
               float* __restrict__ out)
{
    extern __shared__ short lds[];
    const int tid  = threadIdx.x;
    const int lane = tid & 63;
    const int col  = lane & 31;     // batch column within the 32-wide MFMA tile
    const int hi   = lane >> 5;     // lane half
    const int wid  = tid >> 6;      // wave 0..7
    const int row  = blockIdx.x * 256 + wid * 32 + col;

    // ---------------- stage weights: zero, barrier, fill (coalesced reads) ------------
    for (int idx = tid; idx < LDS_SHORTS; idx += 512) lds[idx] = 0;
    __syncthreads();
    for (int idx = tid; idx < 128*128; idx += 512) {       // W2 drift/diff, transposed
        int k = idx >> 7, m = idx & 127;
        lds[OFF_W2D + m*STR2 + k] = bf16s(dw2[idx]);
        lds[OFF_W2F + m*STR2 + k] = bf16s(fw2[idx]);
    }
    for (int idx = tid; idx < 128*64; idx += 512) {        // W3 diff
        int k = idx >> 6, m = idx & 63;
        lds[OFF_W3F + m*STR2 + k] = bf16s(fw3[idx]);
    }
    for (int idx = tid; idx < 128*8; idx += 512) {         // W3 drift (rows 8..31 stay 0)
        int k = idx >> 3, m = idx & 7;
        lds[OFF_W3D + m*STR2 + k] = bf16s(dw3[idx]);
    }
    for (int idx = tid; idx < 9*128; idx += 512) {         // W1 drift/diff (k=0..8)
        int k = idx >> 7, m = idx & 127;
        lds[OFF_W1 + m*STR1 + k]       = bf16s(dw1[idx]);
        lds[OFF_W1 + (m+128)*STR1 + k] = bf16s(fw1[idx]);
    }
    if (tid < 128) {                                       // b1 folded at k=9
        lds[OFF_W1 + tid*STR1 + 9]       = bf16s(db1[tid]);
        lds[OFF_W1 + (tid+128)*STR1 + 9] = bf16s(fb1[tid]);
    }

    const bf16x8 BB = fragU(hi ? 0u : 0x3F80u, 0u, 0u, 0u);  // constant-1 B-frag (bias K-slot)

    // ---------------- initial-condition net: x0 = tanh(noise@iw1+ib1)@iw2+ib2 ----------
    float x[8];
    {
        const float4 n0 = *(const float4*)(noise + (size_t)row*8);
        const float4 n1 = *(const float4*)(noise + (size_t)row*8 + 4);
        bf16x8 Bi = fragU(hi ? pkbf16(1.f,0.f) : pkbf16(n0.x,n0.y),  // bias 1.0 at k=8
                          hi ? 0u : pkbf16(n0.z,n0.w),
                          hi ? 0u : pkbf16(n1.x,n1.y),
                          hi ? 0u : pkbf16(n1.z,n1.w));
        u32 Hf[8][4];
        #pragma unroll
        for (int mt = 0; mt < 4; ++mt) {
            int m = mt*32 + col;
            float wv[8];
            #pragma unroll
            for (int j = 0; j < 8; ++j) {
                int k = hi*8 + j;
                float v = 0.f;
                if (k < 8) v = iw1[(size_t)k*128 + m];
                else if (k == 8) v = ib1[m];
                wv[j] = v;
            }
            bf16x8 A = fragU(pkbf16(wv[0],wv[1]), pkbf16(wv[2],wv[3]),
                             pkbf16(wv[4],wv[5]), pkbf16(wv[6],wv[7]));
            f32x16 dacc = {};
            dacc = mf(A, Bi, dacc);
            transition(dacc, hi, Hf[2*mt], Hf[2*mt+1]);
        }
        f32x16 dx0 = {};
        #pragma unroll
        for (int kt = 0; kt < 8; ++kt) {
            float wv[8];
            #pragma unroll
            for (int j = 0; j < 8; ++j) {
                int k = kt*16 + hi*8 + j;
                wv[j] = (col < 8) ? iw2[(size_t)k*8 + col] : 0.f;
            }
            bf16x8 A = fragU(pkbf16(wv[0],wv[1]), pkbf16(wv[2],wv[3]),
                             pkbf16(wv[4],wv[5]), pkbf16(wv[6],wv[7]));
            dx0 = mf(A, fragU(Hf[kt][0],Hf[kt][1],Hf[kt][2],Hf[kt][3]), dx0);
        }
        u32 ba = (!hi && col < 8) ? pkbf16(ib2[col], 0.f) : 0u;
        dx0 = mf(fragU(ba,0u,0u,0u), BB, dx0);
        #pragma unroll
        for (int r = 0; r < 4; ++r) {          // spread x0 to all lanes of the row pair
            float cv  = dx0[r];
            float clo = hi ? 0.f : cv;
            float chi = hi ? cv  : 0.f;
            x[r]   = clo + __shfl_xor(clo, 32, 64);
            x[r+4] = chi + __shfl_xor(chi, 32, 64);
        }
        float4 o;
        o.x = hi ? x[4] : x[0]; o.y = hi ? x[5] : x[1];
        o.z = hi ? x[6] : x[2]; o.w = hi ? x[7] : x[3];
        *(float4*)(out + (size_t)row*800 + hi*4) = o;       // path[:,0,:]
    }

    // bias A-fragments (1 nonzero dword each)
    u32 ba2d[4], ba2f[4], ba3f[2], ba3d;
    #pragma unroll
    for (int mt = 0; mt < 4; ++mt) {
        ba2d[mt] = hi ? 0u : pkbf16(db2[mt*32+col], 0.f);
        ba2f[mt] = hi ? 0u : pkbf16(fb2[mt*32+col], 0.f);
    }
    ba3f[0] = hi ? 0u : pkbf16(fb3[col], 0.f);
    ba3f[1] = hi ? 0u : pkbf16(fb3[32+col], 0.f);
    ba3d    = (!hi && col < 8) ? pkbf16(db3[col], 0.f) : 0u;

    __syncthreads();

    const short* pW1  = lds + OFF_W1  + col*STR1 + hi*8;
    const short* pW2d = lds + OFF_W2D + col*STR2 + hi*8;
    const short* pW2f = lds + OFF_W2F + col*STR2 + hi*8;
    const short* pW3d = lds + OFF_W3D + col*STR2 + hi*8;
    const short* pW3f = lds + OFF_W3F + col*STR2 + hi*8;

    const float dtv  = 1.0f / 99.0f;
    const float sqdt = sqrtf(dtv);
    const float* dwp = dW + (size_t)row*8 + hi*4;
    float* outp = out + (size_t)row*800 + hi*4;

    #pragma unroll 1
    for (int st = 0; st < 99; ++st) {
        const float tv = (float)st * dtv;
        const float4 dv = *(const float4*)(dwp + (size_t)st * (NB*8));   // own n-half of dW

        // layer-1 B-frag: lo {t,x0..x6}, hi {x7, 1.0(bias k=9)}
        u32 c0 = hi ? pkbf16(x[7], 1.0f) : pkbf16(tv, x[0]);
        u32 c1 = hi ? 0u : pkbf16(x[1], x[2]);
        u32 c2 = hi ? 0u : pkbf16(x[3], x[4]);
        u32 c3 = hi ? 0u : pkbf16(x[5], x[6]);
        bf16x8 B1 = fragU(c0, c1, c2, c3);

        u32 B2d[8][4], B2f[8][4];
        #pragma unroll
        for (int mt = 0; mt < 8; ++mt) {                   // fused drift|diff layer 1
            f32x16 dacc = {};
            dacc = mf(ldsfrag(pW1 + mt*32*STR1), B1, dacc);
            if (mt < 4) transition(dacc, hi, B2d[2*mt], B2d[2*mt+1]);
            else        transition(dacc, hi, B2f[2*(mt-4)], B2f[2*(mt-4)+1]);
        }

        u32 B3[8][4];
        #pragma unroll
        for (int mt = 0; mt < 4; ++mt) {                   // drift layer 2
            f32x16 dacc = {};
            #pragma unroll
            for (int kt = 0; kt < 8; ++kt)
                dacc = mf(ldsfrag(pW2d + mt*32*STR2 + kt*16),
                          fragU(B2d[kt][0],B2d[kt][1],B2d[kt][2],B2d[kt][3]), dacc);
            dacc = mf(fragU(ba2d[mt],0u,0u,0u), BB, dacc);
            transition(dacc, hi, B3[2*mt], B3[2*mt+1]);
        }

        f32x16 fa = {};                                    // drift layer 3 (f)
        #pragma unroll
        for (int kt = 0; kt < 8; ++kt)
            fa = mf(ldsfrag(pW3d + kt*16),
                    fragU(B3[kt][0],B3[kt][1],B3[kt][2],B3[kt][3]), fa);
        fa = mf(fragU(ba3d,0u,0u,0u), BB, fa);
        const float f0 = fa[0], f1 = fa[1], f2 = fa[2], f3 = fa[3];

        #pragma unroll
        for (int mt = 0; mt < 4; ++mt) {                   // diff layer 2
            f32x16 dacc = {};
            #pragma unroll
            for (int kt = 0; kt < 8; ++kt)
                dacc = mf(ldsfrag(pW2f + mt*32*STR2 + kt*16),
                          fragU(B2f[kt][0],B2f[kt][1],B2f[kt][2],B2f[kt][3]), dacc);
            dacc = mf(fragU(ba2f[mt],0u,0u,0u), BB, dacc);
            transition(dacc, hi, B3[2*mt], B3[2*mt+1]);
        }

        float p[8] = {0.f,0.f,0.f,0.f,0.f,0.f,0.f,0.f};
        const float dws[4] = {dv.x*sqdt, dv.y*sqdt, dv.z*sqdt, dv.w*sqdt};
        #pragma unroll
        for (int gt = 0; gt < 2; ++gt) {                   // diff layer 3 (g) + einsum partials
            f32x16 g = {};
            #pragma unroll
            for (int kt = 0; kt < 8; ++kt)
                g = mf(ldsfrag(pW3f + gt*32*STR2 + kt*16),
                       fragU(B3[kt][0],B3[kt][1],B3[kt][2],B3[kt][3]), g);
            g = mf(fragU(ba3f[gt],0u,0u,0u), BB, g);
            #pragma unroll
            for (int r = 0; r < 16; ++r)                   // m = 32gt+(r&3)+8(r>>2)+4hi: d=4gt+(r>>2), n=(r&3)+4hi
                p[gt*4 + (r>>2)] += g[r] * dws[r&3];
        }

        #pragma unroll
        for (int r = 0; r < 4; ++r) {                      // own-half drift term (lane's fa[r] is f[r+4hi])
            float fv = (r==0?f0:r==1?f1:r==2?f2:f3) * dtv;
            p[r]   += hi ? 0.f : fv;
            p[r+4] += hi ? fv  : 0.f;
        }
        #pragma unroll
        for (int d = 0; d < 8; ++d)                        // combine lane halves: dx = own + other
            x[d] += p[d] + __shfl_xor(p[d], 32, 64);

        float4 o;
        o.x = hi ? x[4] : x[0]; o.y = hi ? x[5] : x[1];
        o.z = hi ? x[6] : x[2]; o.w = hi ? x[7] : x[3];
        *(float4*)(outp + (st+1)*8) = o;                   // path[:,st+1,:]
    }
}

extern "C" void kernel_launch(void* const* d_in, const int* in_sizes, int n_in,
                              void* d_out, int out_size, void* d_ws, size_t ws_size,
                              hipStream_t stream) {
    const float* noise = (const float*)d_in[1];
    const float* dW    = (const float*)d_in[2];
    const float* dw1   = (const float*)d_in[3];
    const float* db1   = (const float*)d_in[4];
    const float* dw2   = (const float*)d_in[5];
    const float* db2   = (const float*)d_in[6];
    const float* dw3   = (const float*)d_in[7];
    const float* db3   = (const float*)d_in[8];
    const float* fw1   = (const float*)d_in[9];
    const float* fb1   = (const float*)d_in[10];
    const float* fw2   = (const float*)d_in[11];
    const float* fb2   = (const float*)d_in[12];
    const float* fw3   = (const float*)d_in[13];
    const float* fb3   = (const float*)d_in[14];
    const float* iw1   = (const float*)d_in[15];
    const float* ib1   = (const float*)d_in[16];
    const float* iw2   = (const float*)d_in[17];
    const float* ib2   = (const float*)d_in[18];
    float* out = (float*)d_out;
    sde_fused<<<dim3(256), dim3(512), LDS_SHORTS*sizeof(short), stream>>>(
        noise, dW, dw1, db1, dw2, db2, dw3, db3,
        fw1, fb1, fw2, fb2, fw3, fb3, iw1, ib1, iw2, ib2, out);
}

// Round 3
// 3372.755 us; speedup vs baseline: 1.2711x; 1.2711x over previous
//
#include <hip/hip_runtime.h>

typedef short bf16x8 __attribute__((ext_vector_type(8)));   // 8 bf16 in 4 VGPRs
typedef float f32x16 __attribute__((ext_vector_type(16)));
typedef unsigned int u32;
typedef unsigned int u32x4 __attribute__((ext_vector_type(4)));

#define NB 65536
#define STR2 136                 // LDS row stride (shorts) for K=128 arrays: 272B = 17x16B (odd slots)
#define STR1 24                  // stride for K=16 arrays: 48B = 3x16B
#define OFF_W1  0                // [256][24]   drift|diff layer1 (W^T, k=9 holds b1)
#define OFF_W2D 6144             // [128][136]
#define OFF_W2F 23552            // [128][136]
#define OFF_W3D 40960            // [32][136]  (rows 8..31 zero)
#define OFF_W3F 45312            // [64][136]
#define LDS_SHORTS 54016         // 105.5 KB

// ---- semantics-safe primitives ----
__device__ __forceinline__ u32 bfr(float f) {               // bf16 round-to-nearest-even, raw 16 bits
    u32 u = __builtin_bit_cast(u32, f);
    return (u + 0x7fffu + ((u >> 16) & 1u)) >> 16;
}
__device__ __forceinline__ u32 pkbf16(float a, float b) {   // a -> low16, b -> high16
    return bfr(a) | (bfr(b) << 16);
}
__device__ __forceinline__ short bf16s(float a) {
    return (short)bfr(a);
}
__device__ __forceinline__ float ftanh(float x) {
    float e = __expf(2.0f * x);                             // v_mul + v_exp_f32
    float r = __builtin_amdgcn_rcpf(e + 1.0f);              // fast rcp (~1e-6 rel err, << bf16 eps)
    return __builtin_fmaf(-2.0f, r, 1.0f);
}
__device__ __forceinline__ bf16x8 fragU(u32 a, u32 b, u32 c, u32 d) {
    u32x4 q = {a, b, c, d};
    return __builtin_bit_cast(bf16x8, q);
}
__device__ __forceinline__ bf16x8 fragV(u32x4 q) {
    return __builtin_bit_cast(bf16x8, q);
}
__device__ __forceinline__ bf16x8 ldsfrag(const short* p) {
    const u32x4* q = (const u32x4*)p;                       // ds_read_b128 (16B aligned by construction)
    return __builtin_bit_cast(bf16x8, *q);
}
__device__ __forceinline__ f32x16 mf(bf16x8 a, bf16x8 b, f32x16 c) {
    return __builtin_amdgcn_mfma_f32_32x32x16_bf16(a, b, c, 0, 0, 0);
}

// D tile (post-activation) -> two B-operand K-tiles for the next layer. Returned BY VALUE
// (no address-taken arrays -> SROA keeps everything in VGPRs; round-2's pointer-out-params
// forced B2d/B2f/B3 to scratch: 9.3 GB HBM fetch).
// D reg r in lane (col,hi) holds neuron (r&3)+8*(r>>2)+4*hi of the 32-tile.
struct F2 { u32x4 a, b; };
__device__ __forceinline__ F2 transition(const f32x16 d, int hi) {
    u32 P[8], Q[8];
    #pragma unroll
    for (int i = 0; i < 8; ++i)
        P[i] = pkbf16(ftanh(d[2*i]), ftanh(d[2*i+1]));
    #pragma unroll
    for (int i = 0; i < 8; ++i)
        Q[i] = __shfl_xor(P[i], 32, 64);                    // partner half's value
    F2 r;
    // B-frag dword c of lane (col,hi) must hold k = hi*8 + 2c, 2c+1 of the k-tile
    r.a[0] = hi ? Q[2] : P[0];   r.a[1] = hi ? Q[3] : P[1];
    r.a[2] = hi ? P[2] : Q[0];   r.a[3] = hi ? P[3] : Q[1];
    r.b[0] = hi ? Q[6] : P[4];   r.b[1] = hi ? Q[7] : P[5];
    r.b[2] = hi ? P[6] : Q[4];   r.b[3] = hi ? P[7] : Q[5];
    return r;
}

__global__ __launch_bounds__(512, 2)
void sde_fused(const float* __restrict__ noise, const float* __restrict__ dW,
               const float* __restrict__ dw1, const float* __restrict__ db1,
               const float* __restrict__ dw2, const float* __restrict__ db2,
               const float* __restrict__ dw3, const float* __restrict__ db3,
               const float* __restrict__ fw1, const float* __restrict__ fb1,
               const float* __restrict__ fw2, const float* __restrict__ fb2,
               const float* __restrict__ fw3, const float* __restrict__ fb3,
               const float* __restrict__ iw1, const float* __restrict__ ib1,
               const float* __restrict__ iw2, const float* __restrict__ ib2,
               float* __restrict__ out)
{
    extern __shared__ short lds[];
    const int tid  = threadIdx.x;
    const int lane = tid & 63;
    const int col  = lane & 31;     // batch column within the 32-wide MFMA tile
    const int hi   = lane >> 5;     // lane half
    const int wid  = tid >> 6;      // wave 0..7
    const int row  = blockIdx.x * 256 + wid * 32 + col;

    // ---------------- stage weights: zero, barrier, fill (coalesced reads) ------------
    for (int idx = tid; idx < LDS_SHORTS; idx += 512) lds[idx] = 0;
    __syncthreads();
    for (int idx = tid; idx < 128*128; idx += 512) {       // W2 drift/diff, transposed
        int k = idx >> 7, m = idx & 127;
        lds[OFF_W2D + m*STR2 + k] = bf16s(dw2[idx]);
        lds[OFF_W2F + m*STR2 + k] = bf16s(fw2[idx]);
    }
    for (int idx = tid; idx < 128*64; idx += 512) {        // W3 diff
        int k = idx >> 6, m = idx & 63;
        lds[OFF_W3F + m*STR2 + k] = bf16s(fw3[idx]);
    }
    for (int idx = tid; idx < 128*8; idx += 512) {         // W3 drift (rows 8..31 stay 0)
        int k = idx >> 3, m = idx & 7;
        lds[OFF_W3D + m*STR2 + k] = bf16s(dw3[idx]);
    }
    for (int idx = tid; idx < 9*128; idx += 512) {         // W1 drift/diff (k=0..8)
        int k = idx >> 7, m = idx & 127;
        lds[OFF_W1 + m*STR1 + k]       = bf16s(dw1[idx]);
        lds[OFF_W1 + (m+128)*STR1 + k] = bf16s(fw1[idx]);
    }
    if (tid < 128) {                                       // b1 folded at k=9
        lds[OFF_W1 + tid*STR1 + 9]       = bf16s(db1[tid]);
        lds[OFF_W1 + (tid+128)*STR1 + 9] = bf16s(fb1[tid]);
    }

    const bf16x8 BB = fragU(hi ? 0u : 0x3F80u, 0u, 0u, 0u);  // constant-1 B-frag (bias K-slot)

    // ---------------- initial-condition net: x0 = tanh(noise@iw1+ib1)@iw2+ib2 ----------
    float x[8];
    {
        const float4 n0 = *(const float4*)(noise + (size_t)row*8);
        const float4 n1 = *(const float4*)(noise + (size_t)row*8 + 4);
        bf16x8 Bi = fragU(hi ? pkbf16(1.f,0.f) : pkbf16(n0.x,n0.y),  // bias 1.0 at k=8
                          hi ? 0u : pkbf16(n0.z,n0.w),
                          hi ? 0u : pkbf16(n1.x,n1.y),
                          hi ? 0u : pkbf16(n1.z,n1.w));
        u32x4 Hf[8];
        #pragma unroll
        for (int mt = 0; mt < 4; ++mt) {
            int m = mt*32 + col;
            float wv[8];
            #pragma unroll
            for (int j = 0; j < 8; ++j) {
                int k = hi*8 + j;
                float v = 0.f;
                if (k < 8) v = iw1[(size_t)k*128 + m];
                else if (k == 8) v = ib1[m];
                wv[j] = v;
            }
            bf16x8 A = fragU(pkbf16(wv[0],wv[1]), pkbf16(wv[2],wv[3]),
                             pkbf16(wv[4],wv[5]), pkbf16(wv[6],wv[7]));
            f32x16 dacc = {};
            dacc = mf(A, Bi, dacc);
            F2 t = transition(dacc, hi);
            Hf[2*mt] = t.a; Hf[2*mt+1] = t.b;
        }
        f32x16 dx0 = {};
        #pragma unroll
        for (int kt = 0; kt < 8; ++kt) {
            float wv[8];
            #pragma unroll
            for (int j = 0; j < 8; ++j) {
                int k = kt*16 + hi*8 + j;
                wv[j] = (col < 8) ? iw2[(size_t)k*8 + col] : 0.f;
            }
            bf16x8 A = fragU(pkbf16(wv[0],wv[1]), pkbf16(wv[2],wv[3]),
                             pkbf16(wv[4],wv[5]), pkbf16(wv[6],wv[7]));
            dx0 = mf(A, fragV(Hf[kt]), dx0);
        }
        u32 ba = (!hi && col < 8) ? pkbf16(ib2[col], 0.f) : 0u;
        dx0 = mf(fragU(ba,0u,0u,0u), BB, dx0);
        #pragma unroll
        for (int r = 0; r < 4; ++r) {          // spread x0 to all lanes of the row pair
            float cv  = dx0[r];
            float clo = hi ? 0.f : cv;
            float chi = hi ? cv  : 0.f;
            x[r]   = clo + __shfl_xor(clo, 32, 64);
            x[r+4] = chi + __shfl_xor(chi, 32, 64);
        }
    }

    // bias A-fragments (1 nonzero dword each)
    u32 ba2d[4], ba2f[4], ba3f[2], ba3d;
    #pragma unroll
    for (int mt = 0; mt < 4; ++mt) {
        ba2d[mt] = hi ? 0u : pkbf16(db2[mt*32+col], 0.f);
        ba2f[mt] = hi ? 0u : pkbf16(fb2[mt*32+col], 0.f);
    }
    ba3f[0] = hi ? 0u : pkbf16(fb3[col], 0.f);
    ba3f[1] = hi ? 0u : pkbf16(fb3[32+col], 0.f);
    ba3d    = (!hi && col < 8) ? pkbf16(db3[col], 0.f) : 0u;

    __syncthreads();

    const short* pW1  = lds + OFF_W1  + col*STR1 + hi*8;
    const short* pW2d = lds + OFF_W2D + col*STR2 + hi*8;
    const short* pW2f = lds + OFF_W2F + col*STR2 + hi*8;
    const short* pW3d = lds + OFF_W3D + col*STR2 + hi*8;
    const short* pW3f = lds + OFF_W3F + col*STR2 + hi*8;

    const float dtv  = 1.0f / 99.0f;
    const float sqdt = sqrtf(dtv);
    const float* dwp = dW + (size_t)row*8 + hi*4;
    float* outr = out + (size_t)row*800;       // 3200B row base, 64B-aligned

    float xp[8];                               // previous step's state (for paired 64B line writes)
    #pragma unroll
    for (int d = 0; d < 8; ++d) xp[d] = x[d];

    #pragma unroll 1
    for (int st = 0; st < 99; ++st) {
        const float tv = (float)st * dtv;
        const float4 dv = *(const float4*)(dwp + (size_t)st * (NB*8));   // own n-half of dW

        // layer-1 B-frag: lo {t,x0..x6}, hi {x7, 1.0(bias k=9)}
        u32 c0 = hi ? pkbf16(x[7], 1.0f) : pkbf16(tv, x[0]);
        u32 c1 = hi ? 0u : pkbf16(x[1], x[2]);
        u32 c2 = hi ? 0u : pkbf16(x[3], x[4]);
        u32 c3 = hi ? 0u : pkbf16(x[5], x[6]);
        bf16x8 B1 = fragU(c0, c1, c2, c3);

        // ---------------- drift chain (B2d live only here) ----------------
        u32x4 B2[8], B3[8];
        #pragma unroll
        for (int mt = 0; mt < 4; ++mt) {                   // drift layer 1
            f32x16 dacc = {};
            dacc = mf(ldsfrag(pW1 + mt*32*STR1), B1, dacc);
            F2 t = transition(dacc, hi);
            B2[2*mt] = t.a; B2[2*mt+1] = t.b;
        }
        #pragma unroll
        for (int mt = 0; mt < 4; ++mt) {                   // drift layer 2
            f32x16 dacc = {};
            #pragma unroll
            for (int kt = 0; kt < 8; ++kt)
                dacc = mf(ldsfrag(pW2d + mt*32*STR2 + kt*16), fragV(B2[kt]), dacc);
            dacc = mf(fragU(ba2d[mt],0u,0u,0u), BB, dacc);
            F2 t = transition(dacc, hi);
            B3[2*mt] = t.a; B3[2*mt+1] = t.b;
        }
        f32x16 fa = {};                                    // drift layer 3 (f)
        #pragma unroll
        for (int kt = 0; kt < 8; ++kt)
            fa = mf(ldsfrag(pW3d + kt*16), fragV(B3[kt]), fa);
        fa = mf(fragU(ba3d,0u,0u,0u), BB, fa);
        const float f0 = fa[0], f1 = fa[1], f2 = fa[2], f3 = fa[3];

        // ---------------- diffusion chain (reuses B2/B3 storage) ----------------
        #pragma unroll
        for (int mt = 0; mt < 4; ++mt) {                   // diff layer 1
            f32x16 dacc = {};
            dacc = mf(ldsfrag(pW1 + (mt+4)*32*STR1), B1, dacc);
            F2 t = transition(dacc, hi);
            B2[2*mt] = t.a; B2[2*mt+1] = t.b;
        }
        #pragma unroll
        for (int mt = 0; mt < 4; ++mt) {                   // diff layer 2
            f32x16 dacc = {};
            #pragma unroll
            for (int kt = 0; kt < 8; ++kt)
                dacc = mf(ldsfrag(pW2f + mt*32*STR2 + kt*16), fragV(B2[kt]), dacc);
            dacc = mf(fragU(ba2f[mt],0u,0u,0u), BB, dacc);
            F2 t = transition(dacc, hi);
            B3[2*mt] = t.a; B3[2*mt+1] = t.b;
        }

        float p[8] = {0.f,0.f,0.f,0.f,0.f,0.f,0.f,0.f};
        const float dws[4] = {dv.x*sqdt, dv.y*sqdt, dv.z*sqdt, dv.w*sqdt};
        #pragma unroll
        for (int gt = 0; gt < 2; ++gt) {                   // diff layer 3 (g) + einsum partials
            f32x16 g = {};
            #pragma unroll
            for (int kt = 0; kt < 8; ++kt)
                g = mf(ldsfrag(pW3f + gt*32*STR2 + kt*16), fragV(B3[kt]), g);
            g = mf(fragU(ba3f[gt],0u,0u,0u), BB, g);
            #pragma unroll
            for (int r = 0; r < 16; ++r)                   // m = 32gt+(r&3)+8(r>>2)+4hi: d=4gt+(r>>2), n=(r&3)+4hi
                p[gt*4 + (r>>2)] += g[r] * dws[r&3];
        }

        #pragma unroll
        for (int r = 0; r < 4; ++r) {                      // own-half drift term (lane's fa[r] is f[r+4hi])
            float fv = (r==0?f0:r==1?f1:r==2?f2:f3) * dtv;
            p[r]   += hi ? 0.f : fv;
            p[r+4] += hi ? fv  : 0.f;
        }
        #pragma unroll
        for (int d = 0; d < 8; ++d)                        // combine lane halves: dx = own + other
            x[d] += p[d] + __shfl_xor(p[d], 32, 64);

        // paired output: on even st write the full 64B line [x_st | x_{st+1}]
        // (x_st held in xp; every lane holds the full 8-dim state)
        if ((st & 1) == 0) {
            const float* src = hi ? x : xp;                // hi=0 -> x_st, hi=1 -> x_{st+1}
            float4 o0, o1;
            o0.x = src[0]; o0.y = src[1]; o0.z = src[2]; o0.w = src[3];
            o1.x = src[4]; o1.y = src[5]; o1.z = src[6]; o1.w = src[7];
            float* dst = outr + (size_t)(st + hi) * 8;
            *(float4*)dst       = o0;
            *(float4*)(dst + 4) = o1;
        } else {
            #pragma unroll
            for (int d = 0; d < 8; ++d) xp[d] = x[d];
        }
    }
    // st=98 (even) wrote [x98|x99]; all 100 states stored.
}

extern "C" void kernel_launch(void* const* d_in, const int* in_sizes, int n_in,
                              void* d_out, int out_size, void* d_ws, size_t ws_size,
                              hipStream_t stream) {
    const float* noise = (const float*)d_in[1];
    const float* dW    = (const float*)d_in[2];
    const float* dw1   = (const float*)d_in[3];
    const float* db1   = (const float*)d_in[4];
    const float* dw2   = (const float*)d_in[5];
    const float* db2   = (const float*)d_in[6];
    const float* dw3   = (const float*)d_in[7];
    const float* db3   = (const float*)d_in[8];
    const float* fw1   = (const float*)d_in[9];
    const float* fb1   = (const float*)d_in[10];
    const float* fw2   = (const float*)d_in[11];
    const float* fb2   = (const float*)d_in[12];
    const float* fw3   = (const float*)d_in[13];
    const float* fb3   = (const float*)d_in[14];
    const float* iw1   = (const float*)d_in[15];
    const float* ib1   = (const float*)d_in[16];
    const float* iw2   = (const float*)d_in[17];
    const float* ib2   = (const float*)d_in[18];
    float* out = (float*)d_out;
    sde_fused<<<dim3(256), dim3(512), LDS_SHORTS*sizeof(short), stream>>>(
        noise, dW, dw1, db1, dw2, db2, dw3, db3,
        fw1, fb1, fw2, fb2, fw3, fb3, iw1, ib1, iw2, ib2, out);
}

// Round 4
// 3299.747 us; speedup vs baseline: 1.2992x; 1.0221x over previous
//
#include <hip/hip_runtime.h>

typedef short bf16x8 __attribute__((ext_vector_type(8)));   // 8 bf16 in 4 VGPRs
typedef float f32x16 __attribute__((ext_vector_type(16)));
typedef unsigned int u32;
typedef unsigned int u32x4 __attribute__((ext_vector_type(4)));

#define NB 65536
#define STR2 136                 // LDS row stride (shorts) for K=128 arrays: 272B = 17x16B (odd slots)
#define STR1 24                  // stride for K=16 arrays: 48B = 3x16B
#define OFF_W1  0                // [256][24]   drift|diff layer1 (W^T, kappa-permuted k; b1 at pos 5)
#define OFF_W2D 6144             // [128][136]
#define OFF_W2F 23552            // [128][136]
#define OFF_W3D 40960            // [32][136]  (rows 8..31 zero)
#define OFF_W3F 45312            // [64][136]
#define LDS_SHORTS 54016         // 105.5 KB

// kappa: swap bits 2<->3 within a 16-wide k-tile. Involution. Applied to BOTH the
// A-side (LDS staging) and B-side (transition packing) k-labels, so it cancels in
// D = sum_k A[m][kappa(k)]*B[kappa(k)][n]. Chosen so that a lane's post-MFMA D regs
// (neuron m = (r&3)+8*(r>>2)+4hi) are EXACTLY the next layer's B-fragment in-place:
// tile a = pack(d[0..7]), tile b = pack(d[8..15]), uniform across lanes, no shuffles.
__device__ __host__ __forceinline__ int kappa(int v) {
    return (v & 3) | ((v & 4) << 1) | ((v & 8) >> 1);
}

// ---- semantics-safe primitives ----
__device__ __forceinline__ u32 bfr(float f) {               // bf16 round-to-nearest-even, raw 16 bits
    u32 u = __builtin_bit_cast(u32, f);
    return (u + 0x7fffu + ((u >> 16) & 1u)) >> 16;
}
__device__ __forceinline__ u32 pkbf16(float a, float b) {   // a -> low16, b -> high16
    return bfr(a) | (bfr(b) << 16);
}
__device__ __forceinline__ short bf16s(float a) {
    return (short)bfr(a);
}
__device__ __forceinline__ float ftanh(float x) {
    float e = __expf(2.0f * x);                             // v_mul + v_exp_f32
    float r = __builtin_amdgcn_rcpf(e + 1.0f);              // fast rcp (~1e-6 rel err, << bf16 eps)
    return __builtin_fmaf(-2.0f, r, 1.0f);
}
__device__ __forceinline__ bf16x8 fragU(u32 a, u32 b, u32 c, u32 d) {
    u32x4 q = {a, b, c, d};
    return __builtin_bit_cast(bf16x8, q);
}
__device__ __forceinline__ bf16x8 fragV(u32x4 q) {
    return __builtin_bit_cast(bf16x8, q);
}
__device__ __forceinline__ bf16x8 ldsfrag(const short* p) {
    const u32x4* q = (const u32x4*)p;                       // ds_read_b128 (16B aligned by construction)
    return __builtin_bit_cast(bf16x8, *q);
}
__device__ __forceinline__ f32x16 mf(bf16x8 a, bf16x8 b, f32x16 c) {
    return __builtin_amdgcn_mfma_f32_32x32x16_bf16(a, b, c, 0, 0, 0);
}

// D tile (post-activation) -> two B-operand K-tiles, shuffle-free under kappa.
struct F2 { u32x4 a, b; };
__device__ __forceinline__ F2 transition(const f32x16 d) {
    F2 r;
    r.a[0] = pkbf16(ftanh(d[0]),  ftanh(d[1]));
    r.a[1] = pkbf16(ftanh(d[2]),  ftanh(d[3]));
    r.a[2] = pkbf16(ftanh(d[4]),  ftanh(d[5]));
    r.a[3] = pkbf16(ftanh(d[6]),  ftanh(d[7]));
    r.b[0] = pkbf16(ftanh(d[8]),  ftanh(d[9]));
    r.b[1] = pkbf16(ftanh(d[10]), ftanh(d[11]));
    r.b[2] = pkbf16(ftanh(d[12]), ftanh(d[13]));
    r.b[3] = pkbf16(ftanh(d[14]), ftanh(d[15]));
    return r;
}

__attribute__((amdgpu_waves_per_eu(2, 2)))                  // LDS caps us at 8 waves/CU (2/EU)
__global__ __launch_bounds__(512)                           // anyway -> let regalloc use 256 regs
void sde_fused(const float* __restrict__ noise, const float* __restrict__ dW,
               const float* __restrict__ dw1, const float* __restrict__ db1,
               const float* __restrict__ dw2, const float* __restrict__ db2,
               const float* __restrict__ dw3, const float* __restrict__ db3,
               const float* __restrict__ fw1, const float* __restrict__ fb1,
               const float* __restrict__ fw2, const float* __restrict__ fb2,
               const float* __restrict__ fw3, const float* __restrict__ fb3,
               const float* __restrict__ iw1, const float* __restrict__ ib1,
               const float* __restrict__ iw2, const float* __restrict__ ib2,
               float* __restrict__ out)
{
    extern __shared__ short lds[];
    const int tid  = threadIdx.x;
    const int lane = tid & 63;
    const int col  = lane & 31;     // batch column within the 32-wide MFMA tile
    const int hi   = lane >> 5;     // lane half
    const int wid  = tid >> 6;      // wave 0..7
    const int row  = blockIdx.x * 256 + wid * 32 + col;

    // ---------------- stage weights (kappa-permuted k): zero, barrier, fill -----------
    for (int idx = tid; idx < LDS_SHORTS; idx += 512) lds[idx] = 0;
    __syncthreads();
    for (int idx = tid; idx < 128*128; idx += 512) {       // W2 drift/diff, transposed
        int k = idx >> 7, m = idx & 127;
        int pos = (k & ~15) | kappa(k & 15);
        lds[OFF_W2D + m*STR2 + pos] = bf16s(dw2[idx]);
        lds[OFF_W2F + m*STR2 + pos] = bf16s(fw2[idx]);
    }
    for (int idx = tid; idx < 128*64; idx += 512) {        // W3 diff
        int k = idx >> 6, m = idx & 63;
        int pos = (k & ~15) | kappa(k & 15);
        lds[OFF_W3F + m*STR2 + pos] = bf16s(fw3[idx]);
    }
    for (int idx = tid; idx < 128*8; idx += 512) {         // W3 drift (rows 8..31 stay 0)
        int k = idx >> 3, m = idx & 7;
        int pos = (k & ~15) | kappa(k & 15);
        lds[OFF_W3D + m*STR2 + pos] = bf16s(dw3[idx]);
    }
    for (int idx = tid; idx < 9*128; idx += 512) {         // W1 drift/diff (orig k=0..8)
        int k = idx >> 7, m = idx & 127;
        int pos = kappa(k);
        lds[OFF_W1 + m*STR1 + pos]       = bf16s(dw1[idx]);
        lds[OFF_W1 + (m+128)*STR1 + pos] = bf16s(fw1[idx]);
    }
    if (tid < 128) {                                       // b1 at orig k=9 -> pos 5
        lds[OFF_W1 + tid*STR1 + 5]       = bf16s(db1[tid]);
        lds[OFF_W1 + (tid+128)*STR1 + 5] = bf16s(fb1[tid]);
    }

    const bf16x8 BB = fragU(hi ? 0u : 0x3F80u, 0u, 0u, 0u);  // constant-1 B-frag (k=0 slot)

    // ---------------- initial-condition net: x0 = tanh(noise@iw1+ib1)@iw2+ib2 ----------
    float x[8];
    {
        const float4 n0 = *(const float4*)(noise + (size_t)row*8);
        const float4 n1 = *(const float4*)(noise + (size_t)row*8 + 4);
        // B-frag position (hi,s) holds u[kappa(8hi+s)]; u = (n0..n7, bias@k8)
        bf16x8 Bi = fragU(hi ? pkbf16(n1.x,n1.y) : pkbf16(n0.x,n0.y),
                          hi ? pkbf16(n1.z,n1.w) : pkbf16(n0.z,n0.w),
                          hi ? 0u : pkbf16(1.f,0.f),
                          0u);
        u32x4 Hf[8];
        #pragma unroll
        for (int mt = 0; mt < 4; ++mt) {
            int m = mt*32 + col;
            float wv[8];
            #pragma unroll
            for (int j = 0; j < 8; ++j) {
                int k = kappa(hi*8 + j);                   // orig k this A-slot must hold
                float v = 0.f;
                if (k < 8) v = iw1[(size_t)k*128 + m];
                else if (k == 8) v = ib1[m];
                wv[j] = v;
            }
            bf16x8 A = fragU(pkbf16(wv[0],wv[1]), pkbf16(wv[2],wv[3]),
                             pkbf16(wv[4],wv[5]), pkbf16(wv[6],wv[7]));
            f32x16 dacc = {};
            dacc = mf(A, Bi, dacc);
            F2 t = transition(dacc);
            Hf[2*mt] = t.a; Hf[2*mt+1] = t.b;
        }
        f32x16 dx0 = {};
        #pragma unroll
        for (int kt = 0; kt < 8; ++kt) {
            float wv[8];
            #pragma unroll
            for (int j = 0; j < 8; ++j) {
                int k = kt*16 + kappa(hi*8 + j);
                wv[j] = (col < 8) ? iw2[(size_t)k*8 + col] : 0.f;
            }
            bf16x8 A = fragU(pkbf16(wv[0],wv[1]), pkbf16(wv[2],wv[3]),
                             pkbf16(wv[4],wv[5]), pkbf16(wv[6],wv[7]));
            dx0 = mf(A, fragV(Hf[kt]), dx0);
        }
        u32 ba = (!hi && col < 8) ? pkbf16(ib2[col], 0.f) : 0u;
        dx0 = mf(fragU(ba,0u,0u,0u), BB, dx0);
        #pragma unroll
        for (int r = 0; r < 4; ++r) {          // spread x0 to all lanes of the row pair
            float cv  = dx0[r];
            float clo = hi ? 0.f : cv;
            float chi = hi ? cv  : 0.f;
            x[r]   = clo + __shfl_xor(clo, 32, 64);
            x[r+4] = chi + __shfl_xor(chi, 32, 64);
        }
    }

    // bias A-fragments (1 nonzero dword each; contract with BB's k=0 slot)
    u32 ba2d[4], ba2f[4], ba3f[2], ba3d;
    #pragma unroll
    for (int mt = 0; mt < 4; ++mt) {
        ba2d[mt] = hi ? 0u : pkbf16(db2[mt*32+col], 0.f);
        ba2f[mt] = hi ? 0u : pkbf16(fb2[mt*32+col], 0.f);
    }
    ba3f[0] = hi ? 0u : pkbf16(fb3[col], 0.f);
    ba3f[1] = hi ? 0u : pkbf16(fb3[32+col], 0.f);
    ba3d    = (!hi && col < 8) ? pkbf16(db3[col], 0.f) : 0u;

    __syncthreads();

    const short* pW1  = lds + OFF_W1  + col*STR1 + hi*8;
    const short* pW2d = lds + OFF_W2D + col*STR2 + hi*8;
    const short* pW2f = lds + OFF_W2F + col*STR2 + hi*8;
    const short* pW3d = lds + OFF_W3D + col*STR2 + hi*8;
    const short* pW3f = lds + OFF_W3F + col*STR2 + hi*8;

    const float dtv  = 1.0f / 99.0f;
    const float sqdt = sqrtf(dtv);
    const float* dwp = dW + (size_t)row*8 + hi*4;
    float* outr = out + (size_t)row*800;       // 3200B row base, 64B-aligned

    float xp[8];                               // previous step's state (paired 64B line writes)
    #pragma unroll
    for (int d = 0; d < 8; ++d) xp[d] = x[d];

    #pragma unroll 1
    for (int st = 0; st < 99; ++st) {
        const float tv = (float)st * dtv;
        const float4 dv = *(const float4*)(dwp + (size_t)st * (NB*8));   // own n-half of dW

        // layer-1 B-frag under kappa: u = (t,x0..x7,1.0@k9)
        // hi=0 slots hold u[{0,1,2,3,8,9,..}] ; hi=1 slots hold u[{4,5,6,7,12..}]
        u32 c0 = hi ? pkbf16(x[3], x[4]) : pkbf16(tv, x[0]);
        u32 c1 = hi ? pkbf16(x[5], x[6]) : pkbf16(x[1], x[2]);
        u32 c2 = hi ? 0u : pkbf16(x[7], 1.0f);
        bf16x8 B1 = fragU(c0, c1, c2, 0u);

        // ---------------- drift chain ----------------
        u32x4 B2[8], B3[8];
        #pragma unroll
        for (int mt = 0; mt < 4; ++mt) {                   // drift layer 1
            f32x16 dacc = {};
            dacc = mf(ldsfrag(pW1 + mt*32*STR1), B1, dacc);
            F2 t = transition(dacc);
            B2[2*mt] = t.a; B2[2*mt+1] = t.b;
        }
        #pragma unroll
        for (int mt = 0; mt < 4; ++mt) {                   // drift layer 2
            f32x16 dacc = {};
            #pragma unroll
            for (int kt = 0; kt < 8; ++kt)
                dacc = mf(ldsfrag(pW2d + mt*32*STR2 + kt*16), fragV(B2[kt]), dacc);
            dacc = mf(fragU(ba2d[mt],0u,0u,0u), BB, dacc);
            F2 t = transition(dacc);
            B3[2*mt] = t.a; B3[2*mt+1] = t.b;
        }
        f32x16 fa = {};                                    // drift layer 3 (f)
        #pragma unroll
        for (int kt = 0; kt < 8; ++kt)
            fa = mf(ldsfrag(pW3d + kt*16), fragV(B3[kt]), fa);
        fa = mf(fragU(ba3d,0u,0u,0u), BB, fa);
        const float f0 = fa[0], f1 = fa[1], f2 = fa[2], f3 = fa[3];

        // ---------------- diffusion chain (reuses B2/B3 storage) ----------------
        #pragma unroll
        for (int mt = 0; mt < 4; ++mt) {                   // diff layer 1
            f32x16 dacc = {};
            dacc = mf(ldsfrag(pW1 + (mt+4)*32*STR1), B1, dacc);
            F2 t = transition(dacc);
            B2[2*mt] = t.a; B2[2*mt+1] = t.b;
        }
        #pragma unroll
        for (int mt = 0; mt < 4; ++mt) {                   // diff layer 2
            f32x16 dacc = {};
            #pragma unroll
            for (int kt = 0; kt < 8; ++kt)
                dacc = mf(ldsfrag(pW2f + mt*32*STR2 + kt*16), fragV(B2[kt]), dacc);
            dacc = mf(fragU(ba2f[mt],0u,0u,0u), BB, dacc);
            F2 t = transition(dacc);
            B3[2*mt] = t.a; B3[2*mt+1] = t.b;
        }

        float p[8] = {0.f,0.f,0.f,0.f,0.f,0.f,0.f,0.f};
        const float dws[4] = {dv.x*sqdt, dv.y*sqdt, dv.z*sqdt, dv.w*sqdt};
        #pragma unroll
        for (int gt = 0; gt < 2; ++gt) {                   // diff layer 3 (g) + einsum partials
            f32x16 g = {};
            #pragma unroll
            for (int kt = 0; kt < 8; ++kt)
                g = mf(ldsfrag(pW3f + gt*32*STR2 + kt*16), fragV(B3[kt]), g);
            g = mf(fragU(ba3f[gt],0u,0u,0u), BB, g);
            #pragma unroll
            for (int r = 0; r < 16; ++r)                   // m = 32gt+(r&3)+8(r>>2)+4hi: d=4gt+(r>>2), n=(r&3)+4hi
                p[gt*4 + (r>>2)] += g[r] * dws[r&3];
        }

        #pragma unroll
        for (int r = 0; r < 4; ++r) {                      // own-half drift term (lane's fa[r] is f[r+4hi])
            float fv = (r==0?f0:r==1?f1:r==2?f2:f3) * dtv;
            p[r]   += hi ? 0.f : fv;
            p[r+4] += hi ? fv  : 0.f;
        }
        #pragma unroll
        for (int d = 0; d < 8; ++d)                        // combine lane halves: dx = own + other
            x[d] += p[d] + __shfl_xor(p[d], 32, 64);

        // paired output: on even st write the full 64B line [x_st | x_{st+1}]
        if ((st & 1) == 0) {
            const float* src = hi ? x : xp;                // hi=0 -> x_st, hi=1 -> x_{st+1}
            float4 o0, o1;
            o0.x = src[0]; o0.y = src[1]; o0.z = src[2]; o0.w = src[3];
            o1.x = src[4]; o1.y = src[5]; o1.z = src[6]; o1.w = src[7];
            float* dst = outr + (size_t)(st + hi) * 8;
            *(float4*)dst       = o0;
            *(float4*)(dst + 4) = o1;
        } else {
            #pragma unroll
            for (int d = 0; d < 8; ++d) xp[d] = x[d];
        }
    }
    // st=98 (even) wrote [x98|x99]; all 100 states stored.
}

extern "C" void kernel_launch(void* const* d_in, const int* in_sizes, int n_in,
                              void* d_out, int out_size, void* d_ws, size_t ws_size,
                              hipStream_t stream) {
    const float* noise = (const float*)d_in[1];
    const float* dW    = (const float*)d_in[2];
    const float* dw1   = (const float*)d_in[3];
    const float* db1   = (const float*)d_in[4];
    const float* dw2   = (const float*)d_in[5];
    const float* db2   = (const float*)d_in[6];
    const float* dw3   = (const float*)d_in[7];
    const float* db3   = (const float*)d_in[8];
    const float* fw1   = (const float*)d_in[9];
    const float* fb1   = (const float*)d_in[10];
    const float* fw2   = (const float*)d_in[11];
    const float* fb2   = (const float*)d_in[12];
    const float* fw3   = (const float*)d_in[13];
    const float* fb3   = (const float*)d_in[14];
    const float* iw1   = (const float*)d_in[15];
    const float* ib1   = (const float*)d_in[16];
    const float* iw2   = (const float*)d_in[17];
    const float* ib2   = (const float*)d_in[18];
    float* out = (float*)d_out;
    sde_fused<<<dim3(256), dim3(512), LDS_SHORTS*sizeof(short), stream>>>(
        noise, dW, dw1, db1, dw2, db2, dw3, db3,
        fw1, fb1, fw2, fb2, fw3, fb3, iw1, ib1, iw2, ib2, out);
}